// Round 11
// baseline (166.017 us; speedup 1.0000x reference)
//
#include <hip/hip_runtime.h>
#include <math.h>

typedef float f32x4 __attribute__((ext_vector_type(4)));

#define NF 69u                         // floats per output row (1 + 68)
#define TROWS 64u                      // rows per block-tile
#define TILE_FLOATS (TROWS * NF)       // 4416
#define TILE_F4 (TILE_FLOATS / 4u)     // 1104
#define BLOCK 256u
#define HSTR 13u                       // LDS header row stride (odd -> conflict-free)

__device__ __forceinline__ void pe_coords(unsigned int q, unsigned int W,
                                          unsigned int H, bool pot,
                                          unsigned int lw,
                                          unsigned int& w, unsigned int& h) {
    if (pot) {                  // bench path (512x512): 2 VALU ops
        w = q & (W - 1u);
        h = (q >> lw) & (H - 1u);
    } else {
        const unsigned int t = q / W;
        w = q - t * W;
        h = t % H;
    }
}

// Wave 0 only: compute the 11 header features for row `lane` of tile T and
// write to the LDS header buffer. xv = prefetched x[q]. f32 trig via
// sinpif/cospif; tan via fast divide (threshold 6.48 >> f32 pole error).
__device__ __forceinline__ void pe_headers(float* __restrict__ buf,
                                           unsigned int T, unsigned int Q,
                                           unsigned int W, unsigned int H,
                                           bool pot, unsigned int lw,
                                           unsigned int lane, float xv) {
    const unsigned int q = T * TROWS + lane;
    if (q >= Q) return;
    unsigned int w, h;
    pe_coords(q, W, H, pot, lw, w, h);
    const float wf = (float)w, hf = (float)h;
    const float rw = (W > 1u) ? wf / (float)(W - 1u) : 0.0f;  // matches ref div
    const float rh = (H > 1u) ? hf / (float)(H - 1u) : 0.0f;
    const float nx = (W > 1u) ? 2.0f * rw - 1.0f : 0.0f;
    const float ny = (H > 1u) ? 2.0f * rh - 1.0f : 0.0f;
    const float mx = 0.5f * (float)W, my = 0.5f * (float)H;
    const float sgx = (wf > mx) ? 1.0f : ((wf < mx) ? -1.0f : 0.0f);
    const float sgy = (hf > my) ? 1.0f : ((hf < my) ? -1.0f : 0.0f);
    const float sx = sinpif(rw), cx = cospif(rw);   // rw=0 -> 0,1 (size==1 ok)
    const float sy = sinpif(rh), cy = cospif(rh);
    const float tx = rintf(__fdividef(sx, cx));     // round-half-even = jnp.round
    const float ty = rintf(__fdividef(sy, cy));
    float* r = buf + HSTR * lane;
    r[0] = xv;
    r[1] = nx;  r[2]  = ny;
    r[3] = sgx; r[4]  = sgy;
    r[5] = sx;  r[6]  = sy;
    r[7] = cx;  r[8]  = cy;
    r[9] = tx;  r[10] = ty;
}

// ---------------------------------------------------------------------------
// Single fused kernel. Double-buffered 64-row tiles; per tile: prefetch next
// x -> lgkm-only barrier -> store phase (one-hot computed in registers from
// the tile-invariant (row,f0) pattern; header slots from tiny LDS buffer)
// -> wave 0 computes next tile's headers (trig) into the other buffer.
// ---------------------------------------------------------------------------
__global__ __launch_bounds__(BLOCK) void pe_main_kernel(
    const float* __restrict__ x,
    const int* __restrict__ hptr, const int* __restrict__ wptr,
    float* __restrict__ out, unsigned int Q /* = B*H*W rows */) {
    __shared__ float hdr[2][TROWS * HSTR];   // 2 x 3328 B

    const unsigned int W = (unsigned int)*wptr;
    const unsigned int H = (unsigned int)*hptr;
    const bool pot = ((W & (W - 1u)) == 0u) && ((H & (H - 1u)) == 0u);
    const unsigned int lw = pot ? (unsigned int)(31 - __clz((int)W)) : 0u;
    const unsigned int tid = threadIdx.x;
    const unsigned int lane = tid & 63u;
    const unsigned int wv = tid >> 6;
    const unsigned int ntiles = (Q + TROWS - 1u) / TROWS;
    const unsigned int g = gridDim.x;

    // Tile-invariant per-thread chunk pattern: float4 index tid+256j covers
    // floats starting at (row, f0). Division by literal 69 -> magic-mul.
    unsigned int prow[5], pf0[5];
#pragma unroll
    for (unsigned int j = 0u; j < 5u; ++j) {
        const unsigned int F = 4u * (tid + BLOCK * j);
        prow[j] = F / NF;
        pf0[j] = F - prow[j] * NF;
    }

    unsigned int T = blockIdx.x;
    if (T >= ntiles) return;   // uniform per block

    {   // prologue: headers for tile T into hdr[0]
        float xv = 0.0f;
        if (wv == 0u) {
            const unsigned int q = T * TROWS + lane;
            if (q < Q) xv = x[q];
            pe_headers(hdr[0], T, Q, W, H, pot, lw, lane, xv);
        }
    }
    unsigned int cur = 0u;

    for (; T < ntiles; T += g) {
        const unsigned int Tn = T + g;

        // prefetch next tile's x (wave 0) BEFORE the stores
        float xnext = 0.0f;
        if (wv == 0u && Tn < ntiles) {
            const unsigned int qn = Tn * TROWS + lane;
            if (qn < Q) xnext = x[qn];
        }

        // LDS-only barrier: NT stores stay in flight across it.
        asm volatile("s_waitcnt lgkmcnt(0)\n\ts_barrier" ::: "memory");

        const float* buf = cur ? hdr[1] : hdr[0];
        const unsigned int Trow = T * TROWS;
        const size_t obase = (size_t)T * (size_t)TILE_FLOATS;
        const bool full = (size_t)Trow + TROWS <= (size_t)Q;

        if (full) {
#pragma unroll
            for (unsigned int j = 0u; j < 5u; ++j) {
                if (j < 4u || tid < (TILE_F4 - 4u * BLOCK)) {   // j==4: tid<80
                    const unsigned int row = prow[j], f0 = pf0[j];
                    const unsigned int q = Trow + row;
                    unsigned int w0, h0, w1, h1;
                    pe_coords(q, W, H, pot, lw, w0, h0);
                    pe_coords(q + 1u, W, H, pot, lw, w1, h1);  // wrap row (arith only)
                    f32x4 v;
#pragma unroll
                    for (unsigned int e = 0u; e < 4u; ++e) {
                        unsigned int fm = f0 + e, rr = row, ww = w0, hh = h0;
                        if (fm >= NF) { fm -= NF; rr += 1u; ww = w1; hh = h1; }
                        const float oh = (fm < 40u)
                                             ? ((ww == fm - 11u) ? 1.0f : 0.0f)
                                             : ((hh == fm - 40u) ? 1.0f : 0.0f);
                        v[e] = (fm <= 10u) ? buf[HSTR * rr + fm] : oh;
                    }
                    __builtin_nontemporal_store(
                        v, (f32x4*)(out + obase) + tid + BLOCK * j);
                }
            }
        } else {
            // partial tail tile (not hit for the bench shape)
            const unsigned int rem = Q - Trow;
            const unsigned int nfl = rem * NF;
            for (unsigned int idx = tid; idx < nfl; idx += BLOCK) {
                const unsigned int row = idx / NF;
                const unsigned int fm = idx - row * NF;
                unsigned int ww, hh;
                pe_coords(Trow + row, W, H, pot, lw, ww, hh);
                const float oh = (fm < 40u) ? ((ww == fm - 11u) ? 1.0f : 0.0f)
                                            : ((hh == fm - 40u) ? 1.0f : 0.0f);
                out[obase + idx] = (fm <= 10u) ? buf[HSTR * row + fm] : oh;
            }
        }

        // wave 0: next tile's headers into the other buffer (trig, no loads)
        if (wv == 0u && Tn < ntiles)
            pe_headers(cur ? hdr[0] : hdr[1], Tn, Q, W, H, pot, lw, lane, xnext);
        cur ^= 1u;
    }
}

extern "C" void kernel_launch(void* const* d_in, const int* in_sizes, int n_in,
                              void* d_out, int out_size, void* d_ws, size_t ws_size,
                              hipStream_t stream) {
    const float* x = (const float*)d_in[0];
    const int* hptr = (const int*)d_in[1];
    const int* wptr = (const int*)d_in[2];
    float* out = (float*)d_out;

    const unsigned int Q = (unsigned int)in_sizes[0];  // B*H*W rows
    const unsigned int ntiles = (Q + TROWS - 1u) / TROWS;
    unsigned int blocks = ntiles < 2048u ? ntiles : 2048u;
    if (blocks == 0u) blocks = 1u;
    pe_main_kernel<<<blocks, BLOCK, 0, stream>>>(x, hptr, wptr, out, Q);
}